// Round 1
// baseline (346.178 us; speedup 1.0000x reference)
//
#include <hip/hip_runtime.h>

#define DMODEL   2048
#define NTHREADS 256
#define ROWS_PER_BLK 4              // one 64-lane wave per row
#define CHUNKS   8                  // 8 x float4 per thread per array: 64*4*8 = 2048

typedef float fx4 __attribute__((ext_vector_type(4)));

// sin/cos of theta (radians) via hardware v_sin_f32/v_cos_f32.
// HW takes REVOLUTIONS; fract-reduce first (exact: sin/cos periodic in 1 rev).
// Matches the reference's 4096-entry lerp LUT to ~3e-7; threshold is 2e-2.
__device__ __forceinline__ void fast_sincos(float theta, float& s, float& c) {
    const float INV_TWO_PI = 0.15915494309189535f;
    float r  = theta * INV_TWO_PI;
    float rr = r - floorf(r);                 // [0,1) revolutions
#if __has_builtin(__builtin_amdgcn_sinf) && __has_builtin(__builtin_amdgcn_cosf)
    s = __builtin_amdgcn_sinf(rr);            // v_sin_f32: sin(rr*2pi)
    c = __builtin_amdgcn_cosf(rr);
#else
    s = __sinf(rr * 6.283185307179586f);
    c = __cosf(rr * 6.283185307179586f);
#endif
}

__device__ __forceinline__ float fast_rcp(float x) {
#if __has_builtin(__builtin_amdgcn_rcpf)
    return __builtin_amdgcn_rcpf(x);          // ~1e-7 rel err, plenty for 2e-2
#else
    return 1.0f / x;
#endif
}

template <typename T>
__device__ __forceinline__ void nt_store(T v, T* p) {
#if __has_builtin(__builtin_nontemporal_store)
    __builtin_nontemporal_store(v, p);        // 'nt' flag: don't cache the
#else                                         // write-only output in L2/L3
    *p = v;
#endif
}

// One wave per row: wave-local reduction only (6x shfl_xor), NO LDS, NO
// __syncthreads — waves never wait on each other's vmcnt drain.
// __launch_bounds__(256,4): cap 128 VGPR (4 waves/SIMD); staging peak ~114.
__global__ __launch_bounds__(NTHREADS, 4)
void liquid_echo_kernel(const float* __restrict__ x_real,
                        const float* __restrict__ x_imag,
                        const float* __restrict__ tvec,
                        const float* __restrict__ memory_real,
                        const float* __restrict__ memory_imag,
                        const float* __restrict__ w_trigger,
                        const float* __restrict__ b_trigger,
                        const float* __restrict__ w_state,
                        const float* __restrict__ b_state,
                        const float* __restrict__ kptr,
                        float* __restrict__ out,
                        int nrows,
                        size_t imag_off)
{
    const int lane = threadIdx.x & 63;
    const int row  = blockIdx.x * ROWS_PER_BLK + (threadIdx.x >> 6);
    if (row >= nrows) return;

    const float t_phi = tvec[row] * 1.6180339887498948f;   // PHI
    const size_t rb   = (size_t)row * DMODEL;
    const int cbase   = lane << 2;                          // 16B/lane, coalesced

    // ---- Issue ALL phase-1 row loads up front: 16 float4 = 16 KB MLP/wave
    fx4 xr[CHUNKS], xi[CHUNKS];
    #pragma unroll
    for (int k = 0; k < CHUNKS; ++k) {
        const int c = (k << 8) + cbase;
        xr[k] = *(const fx4*)(x_real + rb + c);
        xi[k] = *(const fx4*)(x_imag + rb + c);
    }

    // ---- Phase 1: trigger via angle-sum identity
    //   trigger_real = cos(th_r + th_i), trigger_imag = sin(th_r + th_i)
    float sxy[CHUNKS * 4];                     // x_r + x_i, reused in phase 2
    float partial = 0.0f;
    #pragma unroll
    for (int k = 0; k < CHUNKS; ++k) {
        const int c = (k << 8) + cbase;
        const fx4 wt = *(const fx4*)(w_trigger + c);   // broadcast, L2-hit
        const fx4 bt = *(const fx4*)(b_trigger + c);
        #pragma unroll
        for (int j = 0; j < 4; ++j) {
            float iw   = fast_rcp(1.0f + fabsf(wt[j]));
            float base = bt[j] + t_phi;
            float sx   = xr[k][j] + xi[k][j];
            sxy[k * 4 + j] = sx;
            float ths  = fmaf(sx, iw, base + base);    // th_r + th_i
            float s, cc;
            fast_sincos(ths, s, cc);
            partial = fmaf(cc, xr[k][j], partial);
            partial = fmaf(s,  xi[k][j], partial);
        }
    }

    // ---- Issue phase-2 memory loads before the reduction (latency overlap)
    fx4 mr[CHUNKS], mi[CHUNKS];
    #pragma unroll
    for (int k = 0; k < CHUNKS; ++k) {
        const int c = (k << 8) + cbase;
        mr[k] = *(const fx4*)(memory_real + rb + c);
        mi[k] = *(const fx4*)(memory_imag + rb + c);
    }

    // ---- Wave-local butterfly reduction: every lane ends with the row total
    #pragma unroll
    for (int off = 32; off > 0; off >>= 1)
        partial += __shfl_xor(partial, off, 64);

    float ic    = partial * (1.0f / 45.254833995939045f);  // / sqrt(2048)
    ic          = fminf(1.0f, fmaxf(-1.0f, ic));
    float x_inv = (1.0f - ic) * 0.5f;
    float k_eff = fabsf(kptr[0]) + 0.1f;
    const float alpha = __expf(-k_eff * x_inv);
    const float oma   = 1.0f - alpha;

    float* outr = out + rb;
    float* outi = out + imag_off + rb;

    // ---- Phase 2: blend + state phase, same identity; nt stores
    #pragma unroll
    for (int k = 0; k < CHUNKS; ++k) {
        const int c = (k << 8) + cbase;
        const fx4 ws = *(const fx4*)(w_state + c);     // broadcast, L2-hit
        const fx4 bs = *(const fx4*)(b_state + c);
        fx4 er, ei;
        #pragma unroll
        for (int j = 0; j < 4; ++j) {
            // (br + bi) = alpha*(xr+xi) + oma*(mr+mi)
            float smm  = mr[k][j] + mi[k][j];
            float sb   = fmaf(alpha, sxy[k * 4 + j], oma * smm);
            float iw   = fast_rcp(1.0f + fabsf(ws[j]));
            float base = bs[j] + t_phi;
            float ths  = fmaf(sb, iw, base + base);    // th_sr + th_si
            float s, cc;
            fast_sincos(ths, s, cc);
            er[j] = cc;                                // cos(sum)
            ei[j] = s;                                 // sin(sum)
        }
        nt_store(er, (fx4*)(outr + c));
        nt_store(ei, (fx4*)(outi + c));
    }
}

extern "C" void kernel_launch(void* const* d_in, const int* in_sizes, int n_in,
                              void* d_out, int out_size, void* d_ws, size_t ws_size,
                              hipStream_t stream) {
    const float* x_real      = (const float*)d_in[0];
    const float* x_imag      = (const float*)d_in[1];
    const float* t           = (const float*)d_in[2];
    const float* memory_real = (const float*)d_in[3];
    const float* memory_imag = (const float*)d_in[4];
    const float* w_trigger   = (const float*)d_in[5];
    const float* b_trigger   = (const float*)d_in[6];
    const float* w_state     = (const float*)d_in[7];
    const float* b_state     = (const float*)d_in[8];
    const float* k           = (const float*)d_in[9];
    // d_in[10], d_in[11] = sin/cos tables — superseded by HW trig (see fast_sincos)
    float* out = (float*)d_out;

    int B = in_sizes[0] / DMODEL;
    size_t imag_off = (size_t)out_size / 2;
    int grid = (B + ROWS_PER_BLK - 1) / ROWS_PER_BLK;

    liquid_echo_kernel<<<grid, NTHREADS, 0, stream>>>(
        x_real, x_imag, t, memory_real, memory_imag,
        w_trigger, b_trigger, w_state, b_state, k,
        out, B, imag_off);
}

// Round 2
// 335.168 us; speedup vs baseline: 1.0328x; 1.0328x over previous
//
#include <hip/hip_runtime.h>

#define DMODEL   2048
#define NTHREADS 256

typedef float fx4 __attribute__((ext_vector_type(4)));

// sin/cos of theta (radians) via hardware v_sin_f32/v_cos_f32.
// HW takes REVOLUTIONS; fract-reduce first (exact: sin/cos periodic in 1 rev).
// Matches the reference's 4096-entry lerp LUT to ~3e-7; threshold is 2e-2.
__device__ __forceinline__ void fast_sincos(float theta, float& s, float& c) {
    const float INV_TWO_PI = 0.15915494309189535f;
    float r  = theta * INV_TWO_PI;
    float rr = r - floorf(r);                 // [0,1) revolutions
#if __has_builtin(__builtin_amdgcn_sinf) && __has_builtin(__builtin_amdgcn_cosf)
    s = __builtin_amdgcn_sinf(rr);            // v_sin_f32: sin(rr*2pi)
    c = __builtin_amdgcn_cosf(rr);
#else
    s = __sinf(rr * 6.283185307179586f);
    c = __cosf(rr * 6.283185307179586f);
#endif
}

__device__ __forceinline__ float fast_rcp(float x) {
#if __has_builtin(__builtin_amdgcn_rcpf)
    return __builtin_amdgcn_rcpf(x);          // ~1e-7 rel err, plenty for 2e-2
#else
    return 1.0f / x;
#endif
}

template <typename T>
__device__ __forceinline__ void nt_store(T v, T* p) {
#if __has_builtin(__builtin_nontemporal_store)
    __builtin_nontemporal_store(v, p);        // write-only output: don't cache
#else
    *p = v;
#endif
}

// Round-0 structure (block-per-row, 4 waves, one barrier) — proven TLP regime.
// Delta vs round 0: ALL 8 HBM row-loads (x_real/x_imag/memory_real/memory_imag,
// 2 float4 each) issue in ONE upfront burst -> single latency exposure per
// block instead of two. w/b params (16 KB total, L2/L3-resident broadcast)
// load just-in-time to keep VGPR < 64 (occupancy cliff at 64: m69).
__global__ __launch_bounds__(NTHREADS)
void liquid_echo_kernel(const float* __restrict__ x_real,
                        const float* __restrict__ x_imag,
                        const float* __restrict__ tvec,
                        const float* __restrict__ memory_real,
                        const float* __restrict__ memory_imag,
                        const float* __restrict__ w_trigger,
                        const float* __restrict__ b_trigger,
                        const float* __restrict__ w_state,
                        const float* __restrict__ b_state,
                        const float* __restrict__ kptr,
                        float* __restrict__ out,
                        size_t imag_off)
{
    __shared__ float red[NTHREADS / 64];

    const int tid = threadIdx.x;
    const int row = blockIdx.x;

    const float t_phi = tvec[row] * 1.6180339887498948f;   // PHI
    const int c0 = tid * 4;
    const int c1 = (DMODEL / 2) + tid * 4;
    const size_t rb = (size_t)row * DMODEL;

    // ---- ONE upfront burst: all 8 HBM loads for this thread (128 B in flight)
    fx4 xr0 = *(const fx4*)(x_real + rb + c0);
    fx4 xr1 = *(const fx4*)(x_real + rb + c1);
    fx4 xi0 = *(const fx4*)(x_imag + rb + c0);
    fx4 xi1 = *(const fx4*)(x_imag + rb + c1);
    fx4 mr0 = *(const fx4*)(memory_real + rb + c0);
    fx4 mr1 = *(const fx4*)(memory_real + rb + c1);
    fx4 mi0 = *(const fx4*)(memory_imag + rb + c0);
    fx4 mi1 = *(const fx4*)(memory_imag + rb + c1);

    // ---- Phase 1: trigger via angle-sum identity
    //   trigger_real = cos(th_r + th_i), trigger_imag = sin(th_r + th_i)
    // w_trigger/b_trigger loaded just-in-time (L2-resident, shared by all rows)
    float sxy[8];                              // x_r + x_i, reused in phase 2
    float smm[8];                              // m_r + m_i
    float partial = 0.0f;
    {
        const fx4 wt0 = *(const fx4*)(w_trigger + c0);
        const fx4 wt1 = *(const fx4*)(w_trigger + c1);
        const fx4 bt0 = *(const fx4*)(b_trigger + c0);
        const fx4 bt1 = *(const fx4*)(b_trigger + c1);
        #pragma unroll
        for (int j = 0; j < 4; ++j) {
            float iw   = fast_rcp(1.0f + fabsf(wt0[j]));
            float base = bt0[j] + t_phi;
            float sx   = xr0[j] + xi0[j];
            sxy[j]     = sx;
            smm[j]     = mr0[j] + mi0[j];
            float ths  = fmaf(sx, iw, base + base);      // th_r + th_i
            float s, c;
            fast_sincos(ths, s, c);
            partial = fmaf(c, xr0[j], partial);
            partial = fmaf(s, xi0[j], partial);
        }
        #pragma unroll
        for (int j = 0; j < 4; ++j) {
            float iw   = fast_rcp(1.0f + fabsf(wt1[j]));
            float base = bt1[j] + t_phi;
            float sx   = xr1[j] + xi1[j];
            sxy[4 + j] = sx;
            smm[4 + j] = mr1[j] + mi1[j];
            float ths  = fmaf(sx, iw, base + base);
            float s, c;
            fast_sincos(ths, s, c);
            partial = fmaf(c, xr1[j], partial);
            partial = fmaf(s, xi1[j], partial);
        }
    }

    // ---- Row reduction: wave shuffle -> 4 partials -> every thread finalizes
    #pragma unroll
    for (int off = 32; off > 0; off >>= 1)
        partial += __shfl_down(partial, off, 64);
    if ((tid & 63) == 0) red[tid >> 6] = partial;
    __syncthreads();

    float tot   = red[0] + red[1] + red[2] + red[3];
    float ic    = tot * (1.0f / 45.254833995939045f);      // / sqrt(2048)
    ic          = fminf(1.0f, fmaxf(-1.0f, ic));
    float x_inv = (1.0f - ic) * 0.5f;
    float k_eff = fabsf(kptr[0]) + 0.1f;
    const float alpha = __expf(-k_eff * x_inv);
    const float oma   = 1.0f - alpha;

    float* outr = out + rb;
    float* outi = out + imag_off + rb;

    // ---- Phase 2: blend + state phase, same identity; nt stores
    {
        const fx4 ws0 = *(const fx4*)(w_state + c0);
        const fx4 ws1 = *(const fx4*)(w_state + c1);
        const fx4 bs0 = *(const fx4*)(b_state + c0);
        const fx4 bs1 = *(const fx4*)(b_state + c1);
        fx4 er, ei;
        #pragma unroll
        for (int j = 0; j < 4; ++j) {
            // (br + bi) = alpha*(xr+xi) + oma*(mr+mi)
            float sb   = fmaf(alpha, sxy[j], oma * smm[j]);
            float iw   = fast_rcp(1.0f + fabsf(ws0[j]));
            float base = bs0[j] + t_phi;
            float ths  = fmaf(sb, iw, base + base);      // th_sr + th_si
            float s, c;
            fast_sincos(ths, s, c);
            er[j] = c;
            ei[j] = s;
        }
        nt_store(er, (fx4*)(outr + c0));
        nt_store(ei, (fx4*)(outi + c0));
        #pragma unroll
        for (int j = 0; j < 4; ++j) {
            float sb   = fmaf(alpha, sxy[4 + j], oma * smm[4 + j]);
            float iw   = fast_rcp(1.0f + fabsf(ws1[j]));
            float base = bs1[j] + t_phi;
            float ths  = fmaf(sb, iw, base + base);
            float s, c;
            fast_sincos(ths, s, c);
            er[j] = c;
            ei[j] = s;
        }
        nt_store(er, (fx4*)(outr + c1));
        nt_store(ei, (fx4*)(outi + c1));
    }
}

extern "C" void kernel_launch(void* const* d_in, const int* in_sizes, int n_in,
                              void* d_out, int out_size, void* d_ws, size_t ws_size,
                              hipStream_t stream) {
    const float* x_real      = (const float*)d_in[0];
    const float* x_imag      = (const float*)d_in[1];
    const float* t           = (const float*)d_in[2];
    const float* memory_real = (const float*)d_in[3];
    const float* memory_imag = (const float*)d_in[4];
    const float* w_trigger   = (const float*)d_in[5];
    const float* b_trigger   = (const float*)d_in[6];
    const float* w_state     = (const float*)d_in[7];
    const float* b_state     = (const float*)d_in[8];
    const float* k           = (const float*)d_in[9];
    // d_in[10], d_in[11] = sin/cos tables — superseded by HW trig (see fast_sincos)
    float* out = (float*)d_out;

    int B = in_sizes[0] / DMODEL;
    size_t imag_off = (size_t)out_size / 2;

    liquid_echo_kernel<<<B, NTHREADS, 0, stream>>>(
        x_real, x_imag, t, memory_real, memory_imag,
        w_trigger, b_trigger, w_state, b_state, k,
        out, imag_off);
}